// Round 2
// baseline (6633.920 us; speedup 1.0000x reference)
//
#include <hip/hip_runtime.h>

#define NB 16
#define NS 12
#define NN 20000
#define NH 128
#define NP 3
#define NE 640000
#define NL 2
#define EPSV 1e-5f
#define NT 313   // ceil(NN/64)

// ---------------- edge dtype detect + normalize ----------------
// If edge_index is int64, every odd int32 word is 0 (values < 2^31).
__global__ void k_detect(const int* __restrict__ ei, int* __restrict__ flag){
  __shared__ int any;
  if(threadIdx.x==0) any=0;
  __syncthreads();
  int nz=0;
  for(int i=threadIdx.x;i<4096;i+=256) if(ei[2*i+1]!=0) nz=1;
  if(nz) atomicOr(&any,1);
  __syncthreads();
  if(threadIdx.x==0) *flag = any ? 0 : 1;   // 1 = int64 layout
}

__global__ void k_extract(const int* __restrict__ ei, const int* __restrict__ flag,
                          int* __restrict__ esrc, int* __restrict__ edst){
  int e = blockIdx.x*256+threadIdx.x;
  if(e<NE){
    int f = *flag;
    int s = f ? ei[2*e]        : ei[e];
    int d = f ? ei[2*NE + 2*e] : ei[NE+e];
    esrc[e]=s; edst[e]=d;
  }
}

// ---------------- graph preprocessing ----------------
__global__ void k_count(const int* __restrict__ esrc, const int* __restrict__ edst,
                        int* __restrict__ deg_src, int* __restrict__ cnt_dst){
  int e = blockIdx.x*256+threadIdx.x;
  if(e<NE){
    atomicAdd(&deg_src[esrc[e]],1);
    atomicAdd(&cnt_dst[edst[e]],1);
  }
}

__global__ void k_dis(const int* __restrict__ deg, float* __restrict__ dis){
  int n = blockIdx.x*256+threadIdx.x;
  if(n<NN) dis[n] = deg[n]>0 ? rsqrtf((float)deg[n]) : 0.f;
}

__global__ __launch_bounds__(1024) void k_scan(const int* __restrict__ cnt, int* __restrict__ offs){
  __shared__ int warpsum[16];
  __shared__ int carry;
  if(threadIdx.x==0) carry=0;
  __syncthreads();
  int lane = threadIdx.x & 63, wid = threadIdx.x >> 6;
  for(int base=0;base<NN;base+=1024){
    int i = base+threadIdx.x;
    int v = (i<NN)?cnt[i]:0;
    int x = v;
    #pragma unroll
    for(int off=1;off<64;off<<=1){
      int y=__shfl_up(x,off,64);
      if(lane>=off) x+=y;
    }
    if(lane==63) warpsum[wid]=x;
    __syncthreads();
    if(wid==0){
      int w=(lane<16)?warpsum[lane]:0;
      #pragma unroll
      for(int off=1;off<16;off<<=1){
        int y=__shfl_up(w,off,64);
        if(lane>=off) w+=y;
      }
      if(lane<16) warpsum[lane]=w;
    }
    __syncthreads();
    int incl = x + ((wid>0)?warpsum[wid-1]:0) + carry;
    if(i<NN) offs[i]=incl-v;
    __syncthreads();
    if(threadIdx.x==1023) carry=incl;
    __syncthreads();
  }
  if(threadIdx.x==0) offs[NN]=carry;
}

__global__ void k_scatter(const int* __restrict__ esrc, const int* __restrict__ edst,
                          const int* __restrict__ offs, int* __restrict__ fill,
                          const float* __restrict__ dis,
                          int* __restrict__ ssorted, float* __restrict__ wsorted){
  int e = blockIdx.x*256+threadIdx.x;
  if(e<NE){
    int s=esrc[e], d=edst[e];
    int pos = offs[d] + atomicAdd(&fill[d],1);
    ssorted[pos]=s;
    wsorted[pos]=-dis[s]*dis[d];
  }
}

// transpose conv weights [L][f][i][kw] -> [L][kw][i][f]
__global__ void k_prepw(const float* __restrict__ cw, float* __restrict__ wt){
  int idx = blockIdx.x*256+threadIdx.x;
  if(idx < NL*3*NH*NH){
    int f = idx & 127;
    int r = idx >> 7;
    int i = r & 127; r >>= 7;
    int kw = r % 3; int l = r / 3;
    wt[idx] = cw[(((l*NH+f)*NH)+i)*3 + kw];
  }
}

// ---------------- input projection (chunk of bc batches starting at b0) ----------------
__global__ __launch_bounds__(256) void k_inproj(const float* __restrict__ x, const float* __restrict__ w,
                                                const float* __restrict__ bb, float* __restrict__ h, int b0){
  __shared__ float ws_[NS*NH];
  __shared__ float bs[NH];
  int t=threadIdx.x;
  for(int i=t;i<NS*NH;i+=256) ws_[i]=w[i];
  if(t<NH) bs[t]=bb[t];
  __syncthreads();
  int idx = blockIdx.x*256+t;
  int f = idx & 127;
  int bn = idx >> 7;
  int bl = bn / NN, n = bn % NN;
  float acc = bs[f];
  const float* xp = x + ((size_t)(b0+bl)*NS)*NN + n;
  #pragma unroll
  for(int s=0;s<NS;s++) acc = fmaf(xp[s*NN], ws_[s*NH+f], acc);
  h[idx]=acc;
}

// ---------------- propagation (CSR gather) ----------------
template<bool COMBINE>
__global__ __launch_bounds__(128) void k_prop(const float* __restrict__ in, const float* __restrict__ sub,
                                              float* __restrict__ out, const int* __restrict__ offs,
                                              const int* __restrict__ ssorted, const float* __restrict__ wsorted){
  int blk = blockIdx.x;                // bl*NN + v
  int bl = blk / NN, v = blk % NN;
  int f = threadIdx.x;
  const float* inb = in + (size_t)bl*NN*NH;
  int e0=offs[v], e1=offs[v+1];
  float acc=0.f;
  for(int e=e0;e<e1;e++){
    acc = fmaf(wsorted[e], inb[ssorted[e]*NH+f], acc);
  }
  size_t o = (size_t)blk*NH+f;
  out[o] = COMBINE ? (2.f*acc - sub[o]) : acc;
}

// ---------------- cheb matmul: t2 <- T0@W0 + T1@W1 + T2@W2 + b (in-place safe, row-aligned) ----------------
__global__ __launch_bounds__(256) void k_cheb(const float* __restrict__ T0, const float* __restrict__ T1,
                                              const float* __restrict__ T2, const float* __restrict__ W,
                                              const float* __restrict__ cb, float* __restrict__ out){
  __shared__ float As[64][33];
  __shared__ float Wsh[32][128];
  __shared__ float bs[128];
  int t = threadIdx.x;
  if(t<128) bs[t]=cb[t];
  int bl = blockIdx.x / NT;
  int m0 = (blockIdx.x % NT) * 64;
  size_t rb = (size_t)bl*NN;
  int tr = t >> 4, tc = t & 15;
  float acc[4][8];
  #pragma unroll
  for(int i=0;i<4;i++)
    #pragma unroll
    for(int j=0;j<8;j++) acc[i][j]=0.f;
  const float* Ts[3] = {T0,T1,T2};
  #pragma unroll
  for(int tm=0; tm<3; tm++){
    const float* A = Ts[tm] + rb*NH;
    for(int kc=0; kc<4; kc++){
      int koff = kc*32;
      __syncthreads();
      #pragma unroll
      for(int q=0;q<2;q++){
        int li = t*2+q;
        int r = li >> 3, c4 = (li & 7)*4;
        int n = m0 + r;
        float4 v = make_float4(0.f,0.f,0.f,0.f);
        if(n<NN) v = *(const float4*)&A[(size_t)n*NH + koff + c4];
        As[r][c4]=v.x; As[r][c4+1]=v.y; As[r][c4+2]=v.z; As[r][c4+3]=v.w;
      }
      #pragma unroll
      for(int q=0;q<4;q++){
        int li = t*4+q;
        int k = li >> 5, f4 = (li & 31)*4;
        float4 v = *(const float4*)&W[tm*NH*NH + (koff+k)*NH + f4];
        Wsh[k][f4]=v.x; Wsh[k][f4+1]=v.y; Wsh[k][f4+2]=v.z; Wsh[k][f4+3]=v.w;
      }
      __syncthreads();
      #pragma unroll
      for(int k=0;k<32;k++){
        float a[4], bv[8];
        #pragma unroll
        for(int i=0;i<4;i++) a[i]=As[tr*4+i][k];
        #pragma unroll
        for(int j=0;j<8;j++) bv[j]=Wsh[k][tc+16*j];
        #pragma unroll
        for(int i=0;i<4;i++)
          #pragma unroll
          for(int j=0;j<8;j++) acc[i][j]=fmaf(a[i],bv[j],acc[i][j]);
      }
    }
  }
  __syncthreads();
  #pragma unroll
  for(int i=0;i<4;i++){
    int n = m0 + tr*4 + i;
    if(n<NN){
      #pragma unroll
      for(int j=0;j<8;j++){
        int f = tc + 16*j;
        out[(rb+n)*NH + f] = acc[i][j] + bs[f];
      }
    }
  }
}

// ---------------- conv1d(node axis) + bias + residual + LN + relu, in-place on H ----------------
__global__ __launch_bounds__(256) void k_conv(const float* __restrict__ Cin, const float* __restrict__ Wt,
                                              const float* __restrict__ cb, const float* __restrict__ lg,
                                              const float* __restrict__ lb, float* __restrict__ H){
  __shared__ float As[66][33];
  __shared__ float Wsh[32][128];
  __shared__ float Cs[64][129];
  __shared__ float cbs[128], gs[128], bbs[128];
  int t=threadIdx.x;
  if(t<128){ cbs[t]=cb[t]; gs[t]=lg[t]; bbs[t]=lb[t]; }
  int bl = blockIdx.x / NT;
  int n0 = (blockIdx.x % NT)*64;
  const float* Cb = Cin + (size_t)bl*NN*NH;
  int tr=t>>4, tc=t&15;
  float acc[4][8];
  #pragma unroll
  for(int i=0;i<4;i++)
    #pragma unroll
    for(int j=0;j<8;j++) acc[i][j]=0.f;
  for(int ic=0;ic<4;ic++){
    __syncthreads();
    for(int li=t; li<66*8; li+=256){
      int r=li>>3, c4=(li&7)*4;
      int n=n0-1+r;
      float4 v=make_float4(0.f,0.f,0.f,0.f);
      if(n>=0&&n<NN) v=*(const float4*)&Cb[(size_t)n*NH + ic*32 + c4];
      As[r][c4]=v.x; As[r][c4+1]=v.y; As[r][c4+2]=v.z; As[r][c4+3]=v.w;
    }
    for(int kw=0;kw<3;kw++){
      __syncthreads();
      #pragma unroll
      for(int q=0;q<4;q++){
        int li=t*4+q;
        int k=li>>5, f4=(li&31)*4;
        float4 v=*(const float4*)&Wt[(kw*NH + ic*32 + k)*NH + f4];
        Wsh[k][f4]=v.x; Wsh[k][f4+1]=v.y; Wsh[k][f4+2]=v.z; Wsh[k][f4+3]=v.w;
      }
      __syncthreads();
      #pragma unroll
      for(int k=0;k<32;k++){
        float a[4],bv[8];
        #pragma unroll
        for(int i=0;i<4;i++) a[i]=As[tr*4+i+kw][k];
        #pragma unroll
        for(int j=0;j<8;j++) bv[j]=Wsh[k][tc+16*j];
        #pragma unroll
        for(int i=0;i<4;i++)
          #pragma unroll
          for(int j=0;j<8;j++) acc[i][j]=fmaf(a[i],bv[j],acc[i][j]);
      }
    }
  }
  __syncthreads();
  #pragma unroll
  for(int i=0;i<4;i++)
    #pragma unroll
    for(int j=0;j<8;j++) Cs[tr*4+i][tc+16*j]=acc[i][j];
  __syncthreads();
  int row=t>>2, part=t&3;
  int n=n0+row;
  float sum=0.f;
  size_t hbase=((size_t)bl*NN+n)*NH;
  if(n<NN){
    #pragma unroll
    for(int jj=0;jj<32;jj++){
      int f=part*32+jj;
      float v=Cs[row][f]+cbs[f]+H[hbase+f];
      Cs[row][f]=v;
      sum+=v;
    }
  }
  sum+=__shfl_xor(sum,1,64); sum+=__shfl_xor(sum,2,64);
  float mu=sum*(1.f/128.f);
  float vs=0.f;
  if(n<NN){
    #pragma unroll
    for(int jj=0;jj<32;jj++){
      float d=Cs[row][part*32+jj]-mu;
      vs+=d*d;
    }
  }
  vs+=__shfl_xor(vs,1,64); vs+=__shfl_xor(vs,2,64);
  float rs=rsqrtf(vs*(1.f/128.f)+EPSV);
  if(n<NN){
    #pragma unroll
    for(int jj=0;jj<32;jj++){
      int f=part*32+jj;
      float y=(Cs[row][f]-mu)*rs*gs[f]+bbs[f];
      H[hbase+f]=fmaxf(y,0.f);
    }
  }
}

// ---------------- output projection + transpose ----------------
__global__ __launch_bounds__(256) void k_out(const float* __restrict__ h, const float* __restrict__ ow,
                                             const float* __restrict__ ob, float* __restrict__ out,
                                             int b0, int total){
  __shared__ float w[NH*NP];
  __shared__ float bs[NP];
  int t=threadIdx.x;
  for(int i=t;i<NH*NP;i+=256) w[i]=ow[i];
  if(t<NP) bs[t]=ob[t];
  __syncthreads();
  int gid = blockIdx.x*256+t;
  if(gid>=total) return;
  int bl = gid / NN, n = gid % NN;
  const float* hp = h + (size_t)gid*NH;
  float a0=bs[0],a1=bs[1],a2=bs[2];
  #pragma unroll
  for(int q=0;q<32;q++){
    float4 v=*(const float4*)&hp[q*4];
    const float* wp=&w[q*12];
    a0=fmaf(v.x,wp[0],a0); a1=fmaf(v.x,wp[1],a1); a2=fmaf(v.x,wp[2],a2);
    a0=fmaf(v.y,wp[3],a0); a1=fmaf(v.y,wp[4],a1); a2=fmaf(v.y,wp[5],a2);
    a0=fmaf(v.z,wp[6],a0); a1=fmaf(v.z,wp[7],a1); a2=fmaf(v.z,wp[8],a2);
    a0=fmaf(v.w,wp[9],a0); a1=fmaf(v.w,wp[10],a1); a2=fmaf(v.w,wp[11],a2);
  }
  size_t b = (size_t)(b0+bl);
  out[(b*NP+0)*NN+n]=a0;
  out[(b*NP+1)*NN+n]=a1;
  out[(b*NP+2)*NN+n]=a2;
}

extern "C" void kernel_launch(void* const* d_in, const int* in_sizes, int n_in,
                              void* d_out, int out_size, void* d_ws, size_t ws_size,
                              hipStream_t stream) {
  const float* x      = (const float*)d_in[0];
  const int*   ei     = (const int*)d_in[1];
  const float* in_w   = (const float*)d_in[2];
  const float* in_b   = (const float*)d_in[3];
  const float* cheb_w = (const float*)d_in[4];
  const float* cheb_b = (const float*)d_in[5];
  const float* conv_w = (const float*)d_in[6];
  const float* conv_b = (const float*)d_in[7];
  const float* ln_g   = (const float*)d_in[8];
  const float* ln_b   = (const float*)d_in[9];
  const float* out_w  = (const float*)d_in[10];
  const float* out_b  = (const float*)d_in[11];
  float* out = (float*)d_out;

  char* ws = (char*)d_ws;
  size_t off = 0;
  auto alloc = [&](size_t bytes)->void*{
    void* p = ws + off;
    off += (bytes + 255) & ~(size_t)255;
    return p;
  };
  // ---- fixed-size region ----
  int* flag    = (int*)alloc(4);
  int* esrc    = (int*)alloc((size_t)NE*4);
  int* edst    = (int*)alloc((size_t)NE*4);
  int* deg     = (int*)alloc(NN*4);
  int* cnt     = (int*)alloc(NN*4);
  int* fill    = (int*)alloc(NN*4);
  int* offs    = (int*)alloc((NN+1)*4);
  float* dis   = (float*)alloc(NN*4);
  int* ssorted = (int*)alloc((size_t)NE*4);
  float* wsorted = (float*)alloc((size_t)NE*4);
  float* wt    = (float*)alloc((size_t)NL*3*NH*NH*4);
  size_t fixed = off;

  // ---- chunk sizing from available workspace ----
  const size_t perbuf = ((size_t)NN*NH*4 + 255) & ~(size_t)255;   // one [N,H] f32 per batch
  size_t avail = (ws_size > fixed) ? (ws_size - fixed) : 0;
  int BC = (int)(avail / (3*perbuf));
  if(BC < 1)  BC = 1;
  if(BC > NB) BC = NB;
  float* h  = (float*)alloc((size_t)BC*perbuf);
  float* t1 = (float*)alloc((size_t)BC*perbuf);
  float* t2 = (float*)alloc((size_t)BC*perbuf);

  hipMemsetAsync(deg, 0, NN*4, stream);
  hipMemsetAsync(cnt, 0, NN*4, stream);
  hipMemsetAsync(fill, 0, NN*4, stream);

  k_detect<<<1,256,0,stream>>>(ei,flag);
  k_extract<<<(NE+255)/256,256,0,stream>>>(ei,flag,esrc,edst);
  k_count<<<(NE+255)/256,256,0,stream>>>(esrc,edst,deg,cnt);
  k_dis<<<(NN+255)/256,256,0,stream>>>(deg,dis);
  k_scan<<<1,1024,0,stream>>>(cnt,offs);
  k_scatter<<<(NE+255)/256,256,0,stream>>>(esrc,edst,offs,fill,dis,ssorted,wsorted);
  k_prepw<<<(NL*3*NH*NH+255)/256,256,0,stream>>>(conv_w,wt);

  for(int b0=0; b0<NB; b0+=BC){
    int bc = NB - b0; if(bc > BC) bc = BC;
    k_inproj<<<bc*10000,256,0,stream>>>(x,in_w,in_b,h,b0);
    for(int l=0;l<NL;l++){
      k_prop<false><<<bc*NN,128,0,stream>>>(h,  nullptr, t1, offs, ssorted, wsorted);
      k_prop<true ><<<bc*NN,128,0,stream>>>(t1, h,       t2, offs, ssorted, wsorted);
      k_cheb<<<bc*NT,256,0,stream>>>(h,t1,t2, cheb_w + (size_t)l*3*NH*NH, cheb_b + l*NH, t2);
      k_conv<<<bc*NT,256,0,stream>>>(t2, wt + (size_t)l*3*NH*NH, conv_b + l*NH,
                                     ln_g + l*NH, ln_b + l*NH, h);
    }
    int total = bc*NN;
    k_out<<<(total+255)/256,256,0,stream>>>(h,out_w,out_b,out,b0,total);
  }
}

// Round 3
// 4622.813 us; speedup vs baseline: 1.4350x; 1.4350x over previous
//
#include <hip/hip_runtime.h>

#define NB 16
#define NS 12
#define NN 20000
#define NH 128
#define NP 3
#define NE 640000
#define NL 2
#define EPSV 1e-5f
#define NT 313   // ceil(NN/64)

typedef __attribute__((ext_vector_type(8))) short short8;
typedef __attribute__((ext_vector_type(4))) float f32x4;

__device__ __forceinline__ unsigned short f2bf(float f){
  unsigned int x = __float_as_uint(f);
  unsigned int r = x + 0x7FFFu + ((x >> 16) & 1u);
  return (unsigned short)(r >> 16);
}
__device__ __forceinline__ unsigned int pack2(float a, float b){
  return (unsigned int)f2bf(a) | ((unsigned int)f2bf(b) << 16);
}
__device__ __forceinline__ float bflo(unsigned int u){ return __uint_as_float(u << 16); }
__device__ __forceinline__ float bfhi(unsigned int u){ return __uint_as_float(u & 0xFFFF0000u); }

// ---------------- edge dtype detect + normalize ----------------
__global__ void k_detect(const int* __restrict__ ei, int* __restrict__ flag){
  __shared__ int any;
  if(threadIdx.x==0) any=0;
  __syncthreads();
  int nz=0;
  for(int i=threadIdx.x;i<4096;i+=256) if(ei[2*i+1]!=0) nz=1;
  if(nz) atomicOr(&any,1);
  __syncthreads();
  if(threadIdx.x==0) *flag = any ? 0 : 1;   // 1 = int64 layout
}

__global__ void k_extract(const int* __restrict__ ei, const int* __restrict__ flag,
                          int* __restrict__ esrc, int* __restrict__ edst){
  int e = blockIdx.x*256+threadIdx.x;
  if(e<NE){
    int f = *flag;
    int s = f ? ei[2*e]        : ei[e];
    int d = f ? ei[2*NE + 2*e] : ei[NE+e];
    esrc[e]=s; edst[e]=d;
  }
}

// ---------------- graph preprocessing ----------------
__global__ void k_count(const int* __restrict__ esrc, const int* __restrict__ edst,
                        int* __restrict__ deg_src, int* __restrict__ cnt_dst){
  int e = blockIdx.x*256+threadIdx.x;
  if(e<NE){
    atomicAdd(&deg_src[esrc[e]],1);
    atomicAdd(&cnt_dst[edst[e]],1);
  }
}

__global__ void k_dis(const int* __restrict__ deg, float* __restrict__ dis){
  int n = blockIdx.x*256+threadIdx.x;
  if(n<NN) dis[n] = deg[n]>0 ? rsqrtf((float)deg[n]) : 0.f;
}

__global__ __launch_bounds__(1024) void k_scan(const int* __restrict__ cnt, int* __restrict__ offs){
  __shared__ int warpsum[16];
  __shared__ int carry;
  if(threadIdx.x==0) carry=0;
  __syncthreads();
  int lane = threadIdx.x & 63, wid = threadIdx.x >> 6;
  for(int base=0;base<NN;base+=1024){
    int i = base+threadIdx.x;
    int v = (i<NN)?cnt[i]:0;
    int x = v;
    #pragma unroll
    for(int off=1;off<64;off<<=1){
      int y=__shfl_up(x,off,64);
      if(lane>=off) x+=y;
    }
    if(lane==63) warpsum[wid]=x;
    __syncthreads();
    if(wid==0){
      int w=(lane<16)?warpsum[lane]:0;
      #pragma unroll
      for(int off=1;off<16;off<<=1){
        int y=__shfl_up(w,off,64);
        if(lane>=off) w+=y;
      }
      if(lane<16) warpsum[lane]=w;
    }
    __syncthreads();
    int incl = x + ((wid>0)?warpsum[wid-1]:0) + carry;
    if(i<NN) offs[i]=incl-v;
    __syncthreads();
    if(threadIdx.x==1023) carry=incl;
    __syncthreads();
  }
  if(threadIdx.x==0) offs[NN]=carry;
}

__global__ void k_scatter(const int* __restrict__ esrc, const int* __restrict__ edst,
                          const int* __restrict__ offs, int* __restrict__ fill,
                          const float* __restrict__ dis,
                          int* __restrict__ ssorted, float* __restrict__ wsorted){
  int e = blockIdx.x*256+threadIdx.x;
  if(e<NE){
    int s=esrc[e], d=edst[e];
    int pos = offs[d] + atomicAdd(&fill[d],1);
    ssorted[pos]=s;
    wsorted[pos]=-dis[s]*dis[d];
  }
}

// weights -> bf16, transposed to B^T layout [f][k]
// Wct[l][tm][f][k] = cheb_w[l][tm][k][f];  Wvt[l][kw][f][i] = conv_w[l][f][i][kw]
__global__ void k_prepw(const float* __restrict__ cw, const float* __restrict__ vw,
                        unsigned short* __restrict__ Wct, unsigned short* __restrict__ Wvt){
  int idx = blockIdx.x*256+threadIdx.x;
  if(idx < NL*3*NH*NH){
    int k = idx & 127;
    int r = idx >> 7;
    int f = r & 127; r >>= 7;
    int sel = r % 3; int l = r / 3;
    Wct[idx] = f2bf(cw[(((l*3+sel)*NH + k)*NH) + f]);
    Wvt[idx] = f2bf(vw[((l*NH + f)*NH + k)*3 + sel]);
  }
}

// ---------------- input projection: h (f32) + hb (bf16 packed) ----------------
__global__ __launch_bounds__(256) void k_inproj(const float* __restrict__ x, const float* __restrict__ w,
                                                const float* __restrict__ bb, float* __restrict__ h,
                                                unsigned int* __restrict__ hbp, int b0){
  __shared__ float ws_[NS*NH];
  __shared__ float bs[NH];
  int t=threadIdx.x;
  for(int i=t;i<NS*NH;i+=256) ws_[i]=w[i];
  if(t<NH) bs[t]=bb[t];
  __syncthreads();
  int gid = blockIdx.x*256+t;          // bc*NN*64
  int f2 = gid & 63;
  int bn = gid >> 6;
  int bl = bn / NN, n = bn % NN;
  const float* xp = x + ((size_t)(b0+bl)*NS)*NN + n;
  float a0 = bs[2*f2], a1 = bs[2*f2+1];
  #pragma unroll
  for(int s=0;s<NS;s++){
    float xv = xp[s*NN];
    a0 = fmaf(xv, ws_[s*NH+2*f2],   a0);
    a1 = fmaf(xv, ws_[s*NH+2*f2+1], a1);
  }
  ((float2*)h)[(size_t)bn*64 + f2] = make_float2(a0,a1);
  hbp[(size_t)bn*64 + f2] = pack2(a0,a1);
}

// ---------------- propagation (CSR gather, bf16 rows, one wave per node) ----------------
template<bool COMBINE>
__global__ __launch_bounds__(256) void k_prop(const unsigned int* __restrict__ in,
                                              const unsigned int* __restrict__ sub,
                                              unsigned int* __restrict__ outp,
                                              const int* __restrict__ offs,
                                              const int* __restrict__ ss,
                                              const float* __restrict__ ws){
  int lane = threadIdx.x & 63, wid = threadIdx.x >> 6;
  int blk = blockIdx.x;                // bl*5000 + vq
  int bl = blk / (NN/4), vq = blk % (NN/4);
  int v = vq*4 + wid;
  const unsigned int* inb = in + (size_t)bl*NN*64;
  int e0=offs[v], e1=offs[v+1];
  float a0=0.f, a1=0.f;
  for(int e=e0;e<e1;e++){
    int s = ss[e]; float w = ws[e];
    unsigned int p = inb[(size_t)s*64 + lane];
    a0 = fmaf(w, bflo(p), a0);
    a1 = fmaf(w, bfhi(p), a1);
  }
  size_t o = ((size_t)bl*NN + v)*64 + lane;
  if(COMBINE){
    unsigned int hv = sub[o];
    a0 = 2.f*a0 - bflo(hv);
    a1 = 2.f*a1 - bfhi(hv);
  }
  outp[o] = pack2(a0,a1);
}

// ---------------- cheb matmul (MFMA): out = T0@W0 + T1@W1 + T2@W2 + b  (bf16 in/out) ----------------
__global__ __launch_bounds__(256) void k_cheb(const unsigned short* __restrict__ T0,
                                              const unsigned short* __restrict__ T1,
                                              const unsigned short* __restrict__ T2,
                                              const unsigned short* __restrict__ Wct,
                                              const float* __restrict__ cb,
                                              unsigned short* __restrict__ outb){
  int t = threadIdx.x;
  int lane = t & 63, w = t >> 6;
  int bl = blockIdx.x / NT;
  int n0 = (blockIdx.x % NT) * 64;
  size_t rb = (size_t)bl*NN;
  int c = lane & 15, g = lane >> 4;
  int rowA = n0 + 16*w + c;
  const unsigned short* Ts[3] = {T0 + rb*NH, T1 + rb*NH, T2 + rb*NH};
  f32x4 acc[8];
  #pragma unroll
  for(int i=0;i<8;i++) acc[i] = (f32x4){0.f,0.f,0.f,0.f};
  short8 zf = {0,0,0,0,0,0,0,0};
  bool okA = rowA < NN;
  for(int kc=0; kc<4; kc++){
    int koff = kc*32 + 8*g;
    #pragma unroll
    for(int tm=0; tm<3; tm++){
      short8 af = okA ? *(const short8*)(Ts[tm] + (size_t)rowA*NH + koff) : zf;
      #pragma unroll
      for(int ft=0; ft<8; ft++){
        short8 bf_ = *(const short8*)(Wct + (((size_t)tm*NH + 16*ft + c)<<7) + koff);
        acc[ft] = __builtin_amdgcn_mfma_f32_16x16x32_bf16(af, bf_, acc[ft], 0, 0, 0);
      }
    }
  }
  // epilogue: + bias, bf16 store.  D: col = lane&15, row = 4*(lane>>4)+reg
  float bias[8];
  #pragma unroll
  for(int ft=0; ft<8; ft++) bias[ft] = cb[16*ft + c];
  #pragma unroll
  for(int r=0;r<4;r++){
    int row = n0 + 16*w + 4*g + r;
    if(row < NN){
      size_t rbase = (rb + row)*NH;
      #pragma unroll
      for(int ft=0; ft<8; ft++)
        outb[rbase + 16*ft + c] = f2bf(acc[ft][r] + bias[ft]);
    }
  }
}

// ---------------- conv1d (MFMA) + bias + residual + LN + relu; updates h (f32) + hb (bf16) ----------------
__global__ __launch_bounds__(256) void k_conv(const unsigned short* __restrict__ Cin,
                                              const unsigned short* __restrict__ Wvt,
                                              const float* __restrict__ cb, const float* __restrict__ lg,
                                              const float* __restrict__ lb,
                                              float* __restrict__ H, unsigned short* __restrict__ Hb){
  int t = threadIdx.x;
  int lane = t & 63, w = t >> 6;
  int bl = blockIdx.x / NT;
  int n0 = (blockIdx.x % NT) * 64;
  size_t rb = (size_t)bl*NN;
  int c = lane & 15, g = lane >> 4;
  const unsigned short* Cb = Cin + rb*NH;
  f32x4 acc[8];
  #pragma unroll
  for(int i=0;i<8;i++) acc[i] = (f32x4){0.f,0.f,0.f,0.f};
  short8 zf = {0,0,0,0,0,0,0,0};
  for(int ic=0; ic<4; ic++){
    int koff = ic*32 + 8*g;
    #pragma unroll
    for(int kw=0; kw<3; kw++){
      int rowA = n0 + 16*w + c + kw - 1;
      short8 af = ((unsigned)rowA < (unsigned)NN) ? *(const short8*)(Cb + (size_t)rowA*NH + koff) : zf;
      #pragma unroll
      for(int ft=0; ft<8; ft++){
        short8 bf_ = *(const short8*)(Wvt + (((size_t)kw*NH + 16*ft + c)<<7) + koff);
        acc[ft] = __builtin_amdgcn_mfma_f32_16x16x32_bf16(af, bf_, acc[ft], 0, 0, 0);
      }
    }
  }
  // epilogue: bias + residual + LN + relu
  float cbv[8], gv[8], bv[8];
  #pragma unroll
  for(int ft=0; ft<8; ft++){
    int f = 16*ft + c;
    cbv[ft] = cb[f]; gv[ft] = lg[f]; bv[ft] = lb[f];
  }
  #pragma unroll
  for(int r=0;r<4;r++){
    int row = n0 + 16*w + 4*g + r;
    bool ok = row < NN;
    size_t rbase = (rb + row)*NH;
    float vals[8];
    float s = 0.f;
    #pragma unroll
    for(int ft=0; ft<8; ft++){
      float res = ok ? H[rbase + 16*ft + c] : 0.f;
      float v = acc[ft][r] + cbv[ft] + res;
      vals[ft] = v;
      s += v;
    }
    s += __shfl_xor(s,1,64); s += __shfl_xor(s,2,64);
    s += __shfl_xor(s,4,64); s += __shfl_xor(s,8,64);
    float mu = s * (1.f/128.f);
    float q = 0.f;
    #pragma unroll
    for(int ft=0; ft<8; ft++){ float d = vals[ft]-mu; q += d*d; }
    q += __shfl_xor(q,1,64); q += __shfl_xor(q,2,64);
    q += __shfl_xor(q,4,64); q += __shfl_xor(q,8,64);
    float rs = rsqrtf(q*(1.f/128.f) + EPSV);
    if(ok){
      #pragma unroll
      for(int ft=0; ft<8; ft++){
        float y = (vals[ft]-mu)*rs*gv[ft] + bv[ft];
        y = fmaxf(y, 0.f);
        H[rbase + 16*ft + c] = y;
        Hb[rbase + 16*ft + c] = f2bf(y);
      }
    }
  }
}

// ---------------- output projection + transpose (reads bf16 h) ----------------
__global__ __launch_bounds__(256) void k_out(const unsigned int* __restrict__ hbp,
                                             const float* __restrict__ ow, const float* __restrict__ ob,
                                             float* __restrict__ out, int b0, int total){
  __shared__ float wsm[NH*NP];
  int t=threadIdx.x;
  for(int i=t;i<NH*NP;i+=256) wsm[i]=ow[i];
  __syncthreads();
  int gid = blockIdx.x*256+t;
  if(gid>=total) return;
  int bl = gid / NN, n = gid % NN;
  const unsigned int* hp = hbp + (size_t)gid*64;
  float a0=ob[0], a1=ob[1], a2=ob[2];
  #pragma unroll
  for(int q=0;q<64;q++){
    unsigned int u = hp[q];
    float f0 = bflo(u), f1 = bfhi(u);
    const float* wp = &wsm[q*6];
    a0=fmaf(f0,wp[0],a0); a1=fmaf(f0,wp[1],a1); a2=fmaf(f0,wp[2],a2);
    a0=fmaf(f1,wp[3],a0); a1=fmaf(f1,wp[4],a1); a2=fmaf(f1,wp[5],a2);
  }
  size_t b = (size_t)(b0+bl);
  out[(b*NP+0)*NN+n]=a0;
  out[(b*NP+1)*NN+n]=a1;
  out[(b*NP+2)*NN+n]=a2;
}

extern "C" void kernel_launch(void* const* d_in, const int* in_sizes, int n_in,
                              void* d_out, int out_size, void* d_ws, size_t ws_size,
                              hipStream_t stream) {
  const float* x      = (const float*)d_in[0];
  const int*   ei     = (const int*)d_in[1];
  const float* in_w   = (const float*)d_in[2];
  const float* in_b   = (const float*)d_in[3];
  const float* cheb_w = (const float*)d_in[4];
  const float* cheb_b = (const float*)d_in[5];
  const float* conv_w = (const float*)d_in[6];
  const float* conv_b = (const float*)d_in[7];
  const float* ln_g   = (const float*)d_in[8];
  const float* ln_b   = (const float*)d_in[9];
  const float* out_w  = (const float*)d_in[10];
  const float* out_b  = (const float*)d_in[11];
  float* out = (float*)d_out;

  char* ws = (char*)d_ws;
  size_t off = 0;
  auto alloc = [&](size_t bytes)->void*{
    void* p = ws + off;
    off += (bytes + 255) & ~(size_t)255;
    return p;
  };
  // ---- fixed region ----
  int* flag    = (int*)alloc(4);
  int* esrc    = (int*)alloc((size_t)NE*4);
  int* edst    = (int*)alloc((size_t)NE*4);
  int* deg     = (int*)alloc(NN*4);
  int* cnt     = (int*)alloc(NN*4);
  int* fill    = (int*)alloc(NN*4);
  int* offs    = (int*)alloc((NN+1)*4);
  float* dis   = (float*)alloc(NN*4);
  int* ssorted = (int*)alloc((size_t)NE*4);
  float* wsorted = (float*)alloc((size_t)NE*4);
  unsigned short* Wct = (unsigned short*)alloc((size_t)NL*3*NH*NH*2);
  unsigned short* Wvt = (unsigned short*)alloc((size_t)NL*3*NH*NH*2);
  size_t fixed = off;

  // ---- chunked activation buffers ----
  const size_t fullb = ((size_t)NN*NH*4 + 255) & ~(size_t)255;
  const size_t halfb = ((size_t)NN*NH*2 + 255) & ~(size_t)255;
  size_t avail = (ws_size > fixed) ? (ws_size - fixed) : 0;
  int BC = (int)(avail / (fullb + 3*halfb));
  if(BC < 1)  BC = 1;
  if(BC > NB) BC = NB;
  float*          h   = (float*)alloc((size_t)BC*fullb);
  unsigned short* hb  = (unsigned short*)alloc((size_t)BC*halfb);
  unsigned short* t1b = (unsigned short*)alloc((size_t)BC*halfb);
  unsigned short* t2b = (unsigned short*)alloc((size_t)BC*halfb);

  hipMemsetAsync(deg, 0, NN*4, stream);
  hipMemsetAsync(cnt, 0, NN*4, stream);
  hipMemsetAsync(fill, 0, NN*4, stream);

  k_detect<<<1,256,0,stream>>>(ei,flag);
  k_extract<<<(NE+255)/256,256,0,stream>>>(ei,flag,esrc,edst);
  k_count<<<(NE+255)/256,256,0,stream>>>(esrc,edst,deg,cnt);
  k_dis<<<(NN+255)/256,256,0,stream>>>(deg,dis);
  k_scan<<<1,1024,0,stream>>>(cnt,offs);
  k_scatter<<<(NE+255)/256,256,0,stream>>>(esrc,edst,offs,fill,dis,ssorted,wsorted);
  k_prepw<<<(NL*3*NH*NH+255)/256,256,0,stream>>>(cheb_w,conv_w,Wct,Wvt);

  for(int b0=0; b0<NB; b0+=BC){
    int bc = NB - b0; if(bc > BC) bc = BC;
    k_inproj<<<bc*(NN/4),256,0,stream>>>(x,in_w,in_b,h,(unsigned int*)hb,b0);
    for(int l=0;l<NL;l++){
      k_prop<false><<<bc*(NN/4),256,0,stream>>>((unsigned int*)hb,  nullptr,
                                                (unsigned int*)t1b, offs, ssorted, wsorted);
      k_prop<true ><<<bc*(NN/4),256,0,stream>>>((unsigned int*)t1b, (unsigned int*)hb,
                                                (unsigned int*)t2b, offs, ssorted, wsorted);
      k_cheb<<<bc*NT,256,0,stream>>>(hb, t1b, t2b, Wct + (size_t)l*3*NH*NH,
                                     cheb_b + l*NH, t2b);
      k_conv<<<bc*NT,256,0,stream>>>(t2b, Wvt + (size_t)l*3*NH*NH, conv_b + l*NH,
                                     ln_g + l*NH, ln_b + l*NH, h, hb);
    }
    int total = bc*NN;
    k_out<<<(total+255)/256,256,0,stream>>>((unsigned int*)hb,out_w,out_b,out,b0,total);
  }
}

// Round 5
// 2709.919 us; speedup vs baseline: 2.4480x; 1.7059x over previous
//
#include <hip/hip_runtime.h>

#define NB 16
#define NS 12
#define NN 20000
#define NH 128
#define NP 3
#define NE 640000
#define NL 2
#define EPSV 1e-5f
#define BCK 8                 // batches per chunk
#define NMC (NN*BCK)          // 160000 rows per chunk (m = n*8 + bl)
#define NTILEC (NMC/64)       // 2500
#define PROP_T (BCK*16)       // 128 threads: BCK*64 uints = BCK*16 uint4 per node

typedef __attribute__((ext_vector_type(8))) short short8;
typedef __attribute__((ext_vector_type(4))) float f32x4;

__device__ __forceinline__ unsigned short f2bf(float f){
  unsigned int x = __float_as_uint(f);
  unsigned int r = x + 0x7FFFu + ((x >> 16) & 1u);
  return (unsigned short)(r >> 16);
}
__device__ __forceinline__ unsigned int pack2(float a, float b){
  return (unsigned int)f2bf(a) | ((unsigned int)f2bf(b) << 16);
}
__device__ __forceinline__ float bflo(unsigned int u){ return __uint_as_float(u << 16); }
__device__ __forceinline__ float bfhi(unsigned int u){ return __uint_as_float(u & 0xFFFF0000u); }

// ---------------- edge dtype detect ----------------
__global__ void k_detect(const int* __restrict__ ei, int* __restrict__ flag){
  __shared__ int any;
  if(threadIdx.x==0) any=0;
  __syncthreads();
  int nz=0;
  for(int i=threadIdx.x;i<4096;i+=256) if(ei[2*i+1]!=0) nz=1;
  if(nz) atomicOr(&any,1);
  __syncthreads();
  if(threadIdx.x==0) *flag = any ? 0 : 1;   // 1 = int64 layout
}

// ---------------- graph preprocessing ----------------
__global__ void k_count(const int* __restrict__ ei, const int* __restrict__ flag,
                        int* __restrict__ deg_src, int* __restrict__ cnt_dst){
  int e = blockIdx.x*256+threadIdx.x;
  if(e<NE){
    int f = *flag;
    int s = f ? ei[2*e]        : ei[e];
    int d = f ? ei[2*NE + 2*e] : ei[NE+e];
    atomicAdd(&deg_src[s],1);
    atomicAdd(&cnt_dst[d],1);
  }
}

__global__ void k_dis(const int* __restrict__ deg, float* __restrict__ dis){
  int n = blockIdx.x*256+threadIdx.x;
  if(n<NN) dis[n] = deg[n]>0 ? rsqrtf((float)deg[n]) : 0.f;
}

__global__ __launch_bounds__(1024) void k_scan(const int* __restrict__ cnt, int* __restrict__ offs){
  __shared__ int warpsum[16];
  __shared__ int carry;
  if(threadIdx.x==0) carry=0;
  __syncthreads();
  int lane = threadIdx.x & 63, wid = threadIdx.x >> 6;
  for(int base=0;base<NN;base+=1024){
    int i = base+threadIdx.x;
    int v = (i<NN)?cnt[i]:0;
    int x = v;
    #pragma unroll
    for(int off=1;off<64;off<<=1){
      int y=__shfl_up(x,off,64);
      if(lane>=off) x+=y;
    }
    if(lane==63) warpsum[wid]=x;
    __syncthreads();
    if(wid==0){
      int w=(lane<16)?warpsum[lane]:0;
      #pragma unroll
      for(int off=1;off<16;off<<=1){
        int y=__shfl_up(w,off,64);
        if(lane>=off) w+=y;
      }
      if(lane<16) warpsum[lane]=w;
    }
    __syncthreads();
    int incl = x + ((wid>0)?warpsum[wid-1]:0) + carry;
    if(i<NN) offs[i]=incl-v;
    __syncthreads();
    if(threadIdx.x==1023) carry=incl;
    __syncthreads();
  }
  if(threadIdx.x==0) offs[NN]=carry;
}

__global__ void k_scatter(const int* __restrict__ ei, const int* __restrict__ flag,
                          const int* __restrict__ offs, int* __restrict__ fill,
                          const float* __restrict__ dis, int2* __restrict__ edata){
  int e = blockIdx.x*256+threadIdx.x;
  if(e<NE){
    int f = *flag;
    int s = f ? ei[2*e]        : ei[e];
    int d = f ? ei[2*NE + 2*e] : ei[NE+e];
    int pos = offs[d] + atomicAdd(&fill[d],1);
    edata[pos] = make_int2(s, __float_as_int(-dis[s]*dis[d]));
  }
}

// weights -> bf16 B^T: Wct[l][tm][f][k] = cheb_w[l][tm][k][f];  Wvt[l][kw][f][i] = conv_w[l][f][i][kw]
__global__ void k_prepw(const float* __restrict__ cw, const float* __restrict__ vw,
                        unsigned short* __restrict__ Wct, unsigned short* __restrict__ Wvt){
  int idx = blockIdx.x*256+threadIdx.x;
  if(idx < NL*3*NH*NH){
    int k = idx & 127;
    int r = idx >> 7;
    int f = r & 127; r >>= 7;
    int sel = r % 3; int l = r / 3;
    Wct[idx] = f2bf(cw[(((l*3+sel)*NH + k)*NH) + f]);
    Wvt[idx] = f2bf(vw[((l*NH + f)*NH + k)*3 + sel]);
  }
}

// ---------------- input projection -> h (f32) + hb (bf16), rows m = n*8 + bl ----------------
__global__ __launch_bounds__(256) void k_inproj(const float* __restrict__ x, const float* __restrict__ w,
                                                const float* __restrict__ bb, float* __restrict__ h,
                                                unsigned int* __restrict__ hb2, int b0){
  __shared__ float ws_[NS*NH];
  int t=threadIdx.x;
  for(int i=t;i<NS*NH;i+=256) ws_[i]=w[i];
  __syncthreads();
  int lane = t & 63;
  int m = blockIdx.x*4 + (t>>6);       // < NMC
  int n = m >> 3, bl = m & 7;
  const float* xp = x + (size_t)(b0+bl)*NS*NN + n;
  float a0 = bb[2*lane], a1 = bb[2*lane+1];
  #pragma unroll
  for(int s=0;s<NS;s++){
    float xv = xp[(size_t)s*NN];
    a0 = fmaf(xv, ws_[s*NH+2*lane],   a0);
    a1 = fmaf(xv, ws_[s*NH+2*lane+1], a1);
  }
  ((float2*)h)[(size_t)m*64 + lane] = make_float2(a0,a1);
  hb2[(size_t)m*64 + lane] = pack2(a0,a1);
}

// ---------------- propagation: block per dst node, 2KB/edge contiguous, unroll x4 ----------------
template<bool COMBINE>
__global__ __launch_bounds__(PROP_T) void k_prop(const uint4* __restrict__ in, const uint4* __restrict__ sub,
                                                 uint4* __restrict__ outp, const int* __restrict__ offs,
                                                 const int2* __restrict__ edata){
  int v = blockIdx.x;
  int t = threadIdx.x;                 // BCK*16 uint4-slots per node
  int e0 = offs[v], e1 = offs[v+1];
  float a0=0.f,a1=0.f,a2=0.f,a3=0.f,a4=0.f,a5=0.f,a6=0.f,a7=0.f;
#define ACC8(P,W) { a0=fmaf(W,bflo(P.x),a0); a1=fmaf(W,bfhi(P.x),a1); \
                    a2=fmaf(W,bflo(P.y),a2); a3=fmaf(W,bfhi(P.y),a3); \
                    a4=fmaf(W,bflo(P.z),a4); a5=fmaf(W,bfhi(P.z),a5); \
                    a6=fmaf(W,bflo(P.w),a6); a7=fmaf(W,bfhi(P.w),a7); }
  int e = e0;
  for(; e+3 < e1; e += 4){
    int2 d0=edata[e], d1=edata[e+1], d2=edata[e+2], d3=edata[e+3];
    uint4 p0 = in[(size_t)d0.x*PROP_T + t];
    uint4 p1 = in[(size_t)d1.x*PROP_T + t];
    uint4 p2 = in[(size_t)d2.x*PROP_T + t];
    uint4 p3 = in[(size_t)d3.x*PROP_T + t];
    ACC8(p0, __int_as_float(d0.y));
    ACC8(p1, __int_as_float(d1.y));
    ACC8(p2, __int_as_float(d2.y));
    ACC8(p3, __int_as_float(d3.y));
  }
  for(; e < e1; e++){
    int2 d = edata[e];
    uint4 p = in[(size_t)d.x*PROP_T + t];
    ACC8(p, __int_as_float(d.y));
  }
#undef ACC8
  size_t o = (size_t)v*PROP_T + t;
  if(COMBINE){
    uint4 hv = sub[o];
    a0 = 2.f*a0 - bflo(hv.x); a1 = 2.f*a1 - bfhi(hv.x);
    a2 = 2.f*a2 - bflo(hv.y); a3 = 2.f*a3 - bfhi(hv.y);
    a4 = 2.f*a4 - bflo(hv.z); a5 = 2.f*a5 - bfhi(hv.z);
    a6 = 2.f*a6 - bflo(hv.w); a7 = 2.f*a7 - bfhi(hv.w);
  }
  uint4 r;
  r.x = pack2(a0,a1); r.y = pack2(a2,a3); r.z = pack2(a4,a5); r.w = pack2(a6,a7);
  outp[o] = r;
}

// ---------------- cheb matmul (MFMA): out = T0@W0 + T1@W1 + T2@W2 + b ----------------
__global__ __launch_bounds__(256) void k_cheb(const unsigned short* __restrict__ T0,
                                              const unsigned short* __restrict__ T1,
                                              const unsigned short* __restrict__ T2,
                                              const unsigned short* __restrict__ Wct,
                                              const float* __restrict__ cb,
                                              unsigned short* __restrict__ outb){
  int t = threadIdx.x;
  int lane = t & 63, w = t >> 6;
  int n0 = blockIdx.x * 64;
  int c = lane & 15, g = lane >> 4;
  int rowA = n0 + 16*w + c;
  const unsigned short* Ts[3] = {T0, T1, T2};
  f32x4 acc[8];
  #pragma unroll
  for(int i=0;i<8;i++) acc[i] = (f32x4){0.f,0.f,0.f,0.f};
  for(int kc=0; kc<4; kc++){
    int koff = kc*32 + 8*g;
    #pragma unroll
    for(int tm=0; tm<3; tm++){
      short8 af = *(const short8*)(Ts[tm] + (size_t)rowA*NH + koff);
      #pragma unroll
      for(int ft=0; ft<8; ft++){
        short8 bf_ = *(const short8*)(Wct + (((size_t)tm*NH + 16*ft + c)<<7) + koff);
        acc[ft] = __builtin_amdgcn_mfma_f32_16x16x32_bf16(af, bf_, acc[ft], 0, 0, 0);
      }
    }
  }
  float bias[8];
  #pragma unroll
  for(int ft=0; ft<8; ft++) bias[ft] = cb[16*ft + c];
  #pragma unroll
  for(int r=0;r<4;r++){
    int row = n0 + 16*w + 4*g + r;
    size_t rbase = (size_t)row*NH;
    #pragma unroll
    for(int ft=0; ft<8; ft++)
      outb[rbase + 16*ft + c] = f2bf(acc[ft][r] + bias[ft]);
  }
}

// ---------------- conv1d (MFMA) + bias + residual(f32) + LN + relu -> h (f32) + hb (bf16) ----------------
__global__ __launch_bounds__(256) void k_conv(const unsigned short* __restrict__ Cin,
                                              const unsigned short* __restrict__ Wvt,
                                              const float* __restrict__ cb, const float* __restrict__ lg,
                                              const float* __restrict__ lb,
                                              float* __restrict__ H, unsigned short* __restrict__ Hb){
  int t = threadIdx.x;
  int lane = t & 63, w = t >> 6;
  int n0 = blockIdx.x * 64;
  int c = lane & 15, g = lane >> 4;
  f32x4 acc[8];
  #pragma unroll
  for(int i=0;i<8;i++) acc[i] = (f32x4){0.f,0.f,0.f,0.f};
  short8 zf = {0,0,0,0,0,0,0,0};
  for(int ic=0; ic<4; ic++){
    int koff = ic*32 + 8*g;
    #pragma unroll
    for(int kw=0; kw<3; kw++){
      int rowA = n0 + 16*w + c + (kw-1)*BCK;     // node neighbor = m +/- BCK
      short8 af = ((unsigned)rowA < (unsigned)NMC) ? *(const short8*)(Cin + (size_t)rowA*NH + koff) : zf;
      #pragma unroll
      for(int ft=0; ft<8; ft++){
        short8 bf_ = *(const short8*)(Wvt + (((size_t)kw*NH + 16*ft + c)<<7) + koff);
        acc[ft] = __builtin_amdgcn_mfma_f32_16x16x32_bf16(af, bf_, acc[ft], 0, 0, 0);
      }
    }
  }
  float cbv[8], gv[8], bv[8];
  #pragma unroll
  for(int ft=0; ft<8; ft++){
    int f = 16*ft + c;
    cbv[ft] = cb[f]; gv[ft] = lg[f]; bv[ft] = lb[f];
  }
  #pragma unroll
  for(int r=0;r<4;r++){
    int row = n0 + 16*w + 4*g + r;
    size_t rbase = (size_t)row*NH;
    float vals[8];
    float s = 0.f;
    #pragma unroll
    for(int ft=0; ft<8; ft++){
      float res = H[rbase + 16*ft + c];
      float v = acc[ft][r] + cbv[ft] + res;
      vals[ft] = v;
      s += v;
    }
    s += __shfl_xor(s,1,64); s += __shfl_xor(s,2,64);
    s += __shfl_xor(s,4,64); s += __shfl_xor(s,8,64);
    float mu = s * (1.f/128.f);
    float q = 0.f;
    #pragma unroll
    for(int ft=0; ft<8; ft++){ float d = vals[ft]-mu; q += d*d; }
    q += __shfl_xor(q,1,64); q += __shfl_xor(q,2,64);
    q += __shfl_xor(q,4,64); q += __shfl_xor(q,8,64);
    float rs = rsqrtf(q*(1.f/128.f) + EPSV);
    #pragma unroll
    for(int ft=0; ft<8; ft++){
      float y = (vals[ft]-mu)*rs*gv[ft] + bv[ft];
      y = fmaxf(y, 0.f);
      H[rbase + 16*ft + c] = y;
      Hb[rbase + 16*ft + c] = f2bf(y);
    }
  }
}

// ---------------- output projection + transpose (LDS-staged) ----------------
__global__ __launch_bounds__(256) void k_out(const unsigned int* __restrict__ hb2,
                                             const float* __restrict__ ow, const float* __restrict__ ob,
                                             float* __restrict__ out, int b0){
  __shared__ unsigned int lds[64*65];
  __shared__ float wsm[NH*NP];
  int t=threadIdx.x;
  for(int i=t;i<NH*NP;i+=256) wsm[i]=ow[i];
  int r0 = blockIdx.x*64;
  for(int i=t;i<4096;i+=256){
    int r = i>>6, q = i&63;
    lds[r*65+q] = hb2[(size_t)(r0+r)*64 + q];
  }
  __syncthreads();
  int row = t>>2, part = t&3;
  float a0=0.f,a1=0.f,a2=0.f;
  #pragma unroll
  for(int j=0;j<16;j++){
    int q = part*16+j;
    unsigned int u = lds[row*65+q];
    float f0=bflo(u), f1=bfhi(u);
    const float* wp=&wsm[q*6];
    a0=fmaf(f0,wp[0],a0); a1=fmaf(f0,wp[1],a1); a2=fmaf(f0,wp[2],a2);
    a0=fmaf(f1,wp[3],a0); a1=fmaf(f1,wp[4],a1); a2=fmaf(f1,wp[5],a2);
  }
  a0+=__shfl_xor(a0,1,64); a0+=__shfl_xor(a0,2,64);
  a1+=__shfl_xor(a1,1,64); a1+=__shfl_xor(a1,2,64);
  a2+=__shfl_xor(a2,1,64); a2+=__shfl_xor(a2,2,64);
  int m = r0+row, n = m>>3, bl = b0 + (m&7);
  if(part==0)      out[((size_t)bl*NP+0)*NN+n]=a0+ob[0];
  else if(part==1) out[((size_t)bl*NP+1)*NN+n]=a1+ob[1];
  else if(part==2) out[((size_t)bl*NP+2)*NN+n]=a2+ob[2];
}

extern "C" void kernel_launch(void* const* d_in, const int* in_sizes, int n_in,
                              void* d_out, int out_size, void* d_ws, size_t ws_size,
                              hipStream_t stream) {
  const float* x      = (const float*)d_in[0];
  const int*   ei     = (const int*)d_in[1];
  const float* in_w   = (const float*)d_in[2];
  const float* in_b   = (const float*)d_in[3];
  const float* cheb_w = (const float*)d_in[4];
  const float* cheb_b = (const float*)d_in[5];
  const float* conv_w = (const float*)d_in[6];
  const float* conv_b = (const float*)d_in[7];
  const float* ln_g   = (const float*)d_in[8];
  const float* ln_b   = (const float*)d_in[9];
  const float* out_w  = (const float*)d_in[10];
  const float* out_b  = (const float*)d_in[11];
  float* out = (float*)d_out;

  char* ws = (char*)d_ws;
  size_t off = 0;
  auto alloc = [&](size_t bytes)->void*{
    void* p = ws + off;
    off += (bytes + 255) & ~(size_t)255;
    return p;
  };
  // ---- fixed region (~6.3 MB) ----
  int* flag    = (int*)alloc(4);
  int* deg     = (int*)alloc(NN*4);
  int* cnt     = (int*)alloc(NN*4);
  int* fill    = (int*)alloc(NN*4);
  int* offs    = (int*)alloc((NN+1)*4);
  float* dis   = (float*)alloc(NN*4);
  int2* edata  = (int2*)alloc((size_t)NE*8);
  unsigned short* Wct = (unsigned short*)alloc((size_t)NL*3*NH*NH*2);
  unsigned short* Wvt = (unsigned short*)alloc((size_t)NL*3*NH*NH*2);
  // ---- chunk activation buffers: 82 + 3*41 MB = 205 MB ----
  const size_t fullb = ((size_t)NMC*NH*4 + 255) & ~(size_t)255;
  const size_t halfb = ((size_t)NMC*NH*2 + 255) & ~(size_t)255;
  float*          h   = (float*)alloc(fullb);
  unsigned short* hb  = (unsigned short*)alloc(halfb);
  unsigned short* t1b = (unsigned short*)alloc(halfb);
  unsigned short* t2b = (unsigned short*)alloc(halfb);

  hipMemsetAsync(deg, 0, NN*4, stream);
  hipMemsetAsync(cnt, 0, NN*4, stream);
  hipMemsetAsync(fill, 0, NN*4, stream);

  k_detect<<<1,256,0,stream>>>(ei,flag);
  k_count<<<(NE+255)/256,256,0,stream>>>(ei,flag,deg,cnt);
  k_dis<<<(NN+255)/256,256,0,stream>>>(deg,dis);
  k_scan<<<1,1024,0,stream>>>(cnt,offs);
  k_scatter<<<(NE+255)/256,256,0,stream>>>(ei,flag,offs,fill,dis,edata);
  k_prepw<<<(NL*3*NH*NH+255)/256,256,0,stream>>>(cheb_w,conv_w,Wct,Wvt);

  for(int b0=0; b0<NB; b0+=BCK){
    k_inproj<<<NMC/4,256,0,stream>>>(x,in_w,in_b,h,(unsigned int*)hb,b0);
    for(int l=0;l<NL;l++){
      k_prop<false><<<NN,PROP_T,0,stream>>>((const uint4*)hb,  nullptr,
                                            (uint4*)t1b, offs, edata);
      k_prop<true ><<<NN,PROP_T,0,stream>>>((const uint4*)t1b, (const uint4*)hb,
                                            (uint4*)t2b, offs, edata);
      k_cheb<<<NTILEC,256,0,stream>>>(hb, t1b, t2b, Wct + (size_t)l*3*NH*NH,
                                      cheb_b + l*NH, t2b);
      k_conv<<<NTILEC,256,0,stream>>>(t2b, Wvt + (size_t)l*3*NH*NH, conv_b + l*NH,
                                      ln_g + l*NH, ln_b + l*NH, h, hb);
    }
    k_out<<<NTILEC,256,0,stream>>>((const unsigned int*)hb,out_w,out_b,out,b0);
  }
}

// Round 7
// 2401.140 us; speedup vs baseline: 2.7628x; 1.1286x over previous
//
#include <hip/hip_runtime.h>

#define NB 16
#define NS 12
#define NN 20000
#define NH 128
#define NP 3
#define NE 640000
#define NL 2
#define EPSV 1e-5f
#define BCK 8                 // batches per chunk
#define NMC (NN*BCK)          // 160000 rows per chunk (m = n*8 + bl)
#define NGEMM (NMC/256)       // 625 blocks for cheb/conv (256 rows per block)
#define PROP_T (BCK*16)       // 128 threads: BCK*64 uints = BCK*16 uint4 per node

typedef __attribute__((ext_vector_type(8))) short short8;
typedef __attribute__((ext_vector_type(4))) float f32x4;
typedef __attribute__((ext_vector_type(4))) unsigned int u32x4;

__device__ __forceinline__ unsigned short f2bf(float f){
  unsigned int x = __float_as_uint(f);
  unsigned int r = x + 0x7FFFu + ((x >> 16) & 1u);
  return (unsigned short)(r >> 16);
}
__device__ __forceinline__ unsigned int pack2(float a, float b){
  return (unsigned int)f2bf(a) | ((unsigned int)f2bf(b) << 16);
}
__device__ __forceinline__ float bflo(unsigned int u){ return __uint_as_float(u << 16); }
__device__ __forceinline__ float bfhi(unsigned int u){ return __uint_as_float(u & 0xFFFF0000u); }

// ---------------- edge dtype detect ----------------
__global__ void k_detect(const int* __restrict__ ei, int* __restrict__ flag){
  __shared__ int any;
  if(threadIdx.x==0) any=0;
  __syncthreads();
  int nz=0;
  for(int i=threadIdx.x;i<4096;i+=256) if(ei[2*i+1]!=0) nz=1;
  if(nz) atomicOr(&any,1);
  __syncthreads();
  if(threadIdx.x==0) *flag = any ? 0 : 1;   // 1 = int64 layout
}

// ---------------- graph preprocessing ----------------
__global__ void k_count(const int* __restrict__ ei, const int* __restrict__ flag,
                        int* __restrict__ deg_src, int* __restrict__ cnt_dst){
  int e = blockIdx.x*256+threadIdx.x;
  if(e<NE){
    int f = *flag;
    int s = f ? ei[2*e]        : ei[e];
    int d = f ? ei[2*NE + 2*e] : ei[NE+e];
    atomicAdd(&deg_src[s],1);
    atomicAdd(&cnt_dst[d],1);
  }
}

__global__ void k_dis(const int* __restrict__ deg, float* __restrict__ dis){
  int n = blockIdx.x*256+threadIdx.x;
  if(n<NN) dis[n] = deg[n]>0 ? rsqrtf((float)deg[n]) : 0.f;
}

__global__ __launch_bounds__(1024) void k_scan(const int* __restrict__ cnt, int* __restrict__ offs){
  __shared__ int warpsum[16];
  __shared__ int carry;
  if(threadIdx.x==0) carry=0;
  __syncthreads();
  int lane = threadIdx.x & 63, wid = threadIdx.x >> 6;
  for(int base=0;base<NN;base+=1024){
    int i = base+threadIdx.x;
    int v = (i<NN)?cnt[i]:0;
    int x = v;
    #pragma unroll
    for(int off=1;off<64;off<<=1){
      int y=__shfl_up(x,off,64);
      if(lane>=off) x+=y;
    }
    if(lane==63) warpsum[wid]=x;
    __syncthreads();
    if(wid==0){
      int w=(lane<16)?warpsum[lane]:0;
      #pragma unroll
      for(int off=1;off<16;off<<=1){
        int y=__shfl_up(w,off,64);
        if(lane>=off) w+=y;
      }
      if(lane<16) warpsum[lane]=w;
    }
    __syncthreads();
    int incl = x + ((wid>0)?warpsum[wid-1]:0) + carry;
    if(i<NN) offs[i]=incl-v;
    __syncthreads();
    if(threadIdx.x==1023) carry=incl;
    __syncthreads();
  }
  if(threadIdx.x==0) offs[NN]=carry;
}

__global__ void k_scatter(const int* __restrict__ ei, const int* __restrict__ flag,
                          const int* __restrict__ offs, int* __restrict__ fill,
                          const float* __restrict__ dis, int2* __restrict__ edata){
  int e = blockIdx.x*256+threadIdx.x;
  if(e<NE){
    int f = *flag;
    int s = f ? ei[2*e]        : ei[e];
    int d = f ? ei[2*NE + 2*e] : ei[NE+e];
    int pos = offs[d] + atomicAdd(&fill[d],1);
    edata[pos] = make_int2(s, __float_as_int(-dis[s]*dis[d]));
  }
}

// weights -> bf16 B^T: Wct[l][tm][f][k] = cheb_w[l][tm][k][f];  Wvt[l][kw][f][i] = conv_w[l][f][i][kw]
__global__ void k_prepw(const float* __restrict__ cw, const float* __restrict__ vw,
                        unsigned short* __restrict__ Wct, unsigned short* __restrict__ Wvt){
  int idx = blockIdx.x*256+threadIdx.x;
  if(idx < NL*3*NH*NH){
    int k = idx & 127;
    int r = idx >> 7;
    int f = r & 127; r >>= 7;
    int sel = r % 3; int l = r / 3;
    Wct[idx] = f2bf(cw[(((l*3+sel)*NH + k)*NH) + f]);
    Wvt[idx] = f2bf(vw[((l*NH + f)*NH + k)*3 + sel]);
  }
}

// ---------------- input projection -> h (f32) + hb (bf16), rows m = n*8 + bl ----------------
__global__ __launch_bounds__(256) void k_inproj(const float* __restrict__ x, const float* __restrict__ w,
                                                const float* __restrict__ bb, float* __restrict__ h,
                                                unsigned int* __restrict__ hb2, int b0){
  __shared__ float ws_[NS*NH];
  int t=threadIdx.x;
  for(int i=t;i<NS*NH;i+=256) ws_[i]=w[i];
  __syncthreads();
  int lane = t & 63;
  int m = blockIdx.x*4 + (t>>6);       // < NMC
  int n = m >> 3, bl = m & 7;
  const float* xp = x + (size_t)(b0+bl)*NS*NN + n;
  float a0 = bb[2*lane], a1 = bb[2*lane+1];
  #pragma unroll
  for(int s=0;s<NS;s++){
    float xv = xp[(size_t)s*NN];
    a0 = fmaf(xv, ws_[s*NH+2*lane],   a0);
    a1 = fmaf(xv, ws_[s*NH+2*lane+1], a1);
  }
  ((float2*)h)[(size_t)m*64 + lane] = make_float2(a0,a1);
  hb2[(size_t)m*64 + lane] = pack2(a0,a1);
}

// ---------------- propagation: block per dst node, 2KB/edge contiguous, unroll x8, nt store ----------------
template<bool COMBINE>
__global__ __launch_bounds__(PROP_T) void k_prop(const uint4* __restrict__ in, const uint4* __restrict__ sub,
                                                 uint4* __restrict__ outp, const int* __restrict__ offs,
                                                 const int2* __restrict__ edata){
  int v = blockIdx.x;
  int t = threadIdx.x;                 // BCK*16 uint4-slots per node
  int e0 = offs[v], e1 = offs[v+1];
  size_t o = (size_t)v*PROP_T + t;
  uint4 hv;
  if(COMBINE) hv = sub[o];
  float a0=0.f,a1=0.f,a2=0.f,a3=0.f,a4=0.f,a5=0.f,a6=0.f,a7=0.f;
#define ACC8(P,W) { a0=fmaf(W,bflo(P.x),a0); a1=fmaf(W,bfhi(P.x),a1); \
                    a2=fmaf(W,bflo(P.y),a2); a3=fmaf(W,bfhi(P.y),a3); \
                    a4=fmaf(W,bflo(P.z),a4); a5=fmaf(W,bfhi(P.z),a5); \
                    a6=fmaf(W,bflo(P.w),a6); a7=fmaf(W,bfhi(P.w),a7); }
  int e = e0;
  for(; e+7 < e1; e += 8){
    int2 d0=edata[e],   d1=edata[e+1], d2=edata[e+2], d3=edata[e+3];
    int2 d4=edata[e+4], d5=edata[e+5], d6=edata[e+6], d7=edata[e+7];
    uint4 p0 = in[(size_t)d0.x*PROP_T + t];
    uint4 p1 = in[(size_t)d1.x*PROP_T + t];
    uint4 p2 = in[(size_t)d2.x*PROP_T + t];
    uint4 p3 = in[(size_t)d3.x*PROP_T + t];
    uint4 p4 = in[(size_t)d4.x*PROP_T + t];
    uint4 p5 = in[(size_t)d5.x*PROP_T + t];
    uint4 p6 = in[(size_t)d6.x*PROP_T + t];
    uint4 p7 = in[(size_t)d7.x*PROP_T + t];
    ACC8(p0, __int_as_float(d0.y)); ACC8(p1, __int_as_float(d1.y));
    ACC8(p2, __int_as_float(d2.y)); ACC8(p3, __int_as_float(d3.y));
    ACC8(p4, __int_as_float(d4.y)); ACC8(p5, __int_as_float(d5.y));
    ACC8(p6, __int_as_float(d6.y)); ACC8(p7, __int_as_float(d7.y));
  }
  for(; e+3 < e1; e += 4){
    int2 d0=edata[e], d1=edata[e+1], d2=edata[e+2], d3=edata[e+3];
    uint4 p0 = in[(size_t)d0.x*PROP_T + t];
    uint4 p1 = in[(size_t)d1.x*PROP_T + t];
    uint4 p2 = in[(size_t)d2.x*PROP_T + t];
    uint4 p3 = in[(size_t)d3.x*PROP_T + t];
    ACC8(p0, __int_as_float(d0.y)); ACC8(p1, __int_as_float(d1.y));
    ACC8(p2, __int_as_float(d2.y)); ACC8(p3, __int_as_float(d3.y));
  }
  for(; e < e1; e++){
    int2 d = edata[e];
    uint4 p = in[(size_t)d.x*PROP_T + t];
    ACC8(p, __int_as_float(d.y));
  }
#undef ACC8
  if(COMBINE){
    a0 = 2.f*a0 - bflo(hv.x); a1 = 2.f*a1 - bfhi(hv.x);
    a2 = 2.f*a2 - bflo(hv.y); a3 = 2.f*a3 - bfhi(hv.y);
    a4 = 2.f*a4 - bflo(hv.z); a5 = 2.f*a5 - bfhi(hv.z);
    a6 = 2.f*a6 - bflo(hv.w); a7 = 2.f*a7 - bfhi(hv.w);
  }
  u32x4 r;
  r.x = pack2(a0,a1); r.y = pack2(a2,a3); r.z = pack2(a4,a5); r.w = pack2(a6,a7);
  __builtin_nontemporal_store(r, (u32x4*)&outp[o]);
}

// ---------------- cheb matmul (MFMA, 64 rows/wave): out = T0@W0 + T1@W1 + T2@W2 + b ----------------
__global__ __launch_bounds__(256) void k_cheb(const unsigned short* __restrict__ T0,
                                              const unsigned short* __restrict__ T1,
                                              const unsigned short* __restrict__ T2,
                                              const unsigned short* __restrict__ Wct,
                                              const float* __restrict__ cb,
                                              unsigned short* __restrict__ outb){
  int t = threadIdx.x;
  int lane = t & 63, w = t >> 6;
  int c = lane & 15, g = lane >> 4;
  int rbase = blockIdx.x*256 + w*64;
  const unsigned short* Ts[3] = {T0, T1, T2};
  f32x4 acc[4][8];
  #pragma unroll
  for(int i=0;i<4;i++)
    #pragma unroll
    for(int j=0;j<8;j++) acc[i][j] = (f32x4){0.f,0.f,0.f,0.f};
  for(int kc=0; kc<4; kc++){
    int koff = kc*32 + 8*g;
    #pragma unroll
    for(int tm=0; tm<3; tm++){
      short8 af[4];
      #pragma unroll
      for(int rt=0; rt<4; rt++)
        af[rt] = *(const short8*)(Ts[tm] + (size_t)(rbase + rt*16 + c)*NH + koff);
      #pragma unroll
      for(int ft=0; ft<8; ft++){
        short8 bf_ = *(const short8*)(Wct + (((size_t)tm*NH + 16*ft + c)<<7) + koff);
        #pragma unroll
        for(int rt=0; rt<4; rt++)
          acc[rt][ft] = __builtin_amdgcn_mfma_f32_16x16x32_bf16(af[rt], bf_, acc[rt][ft], 0, 0, 0);
      }
    }
  }
  float bias[8];
  #pragma unroll
  for(int ft=0; ft<8; ft++) bias[ft] = cb[16*ft + c];
  #pragma unroll
  for(int rt=0; rt<4; rt++){
    #pragma unroll
    for(int r=0;r<4;r++){
      int row = rbase + rt*16 + 4*g + r;
      size_t rbs = (size_t)row*NH;
      #pragma unroll
      for(int ft=0; ft<8; ft++)
        outb[rbs + 16*ft + c] = f2bf(acc[rt][ft][r] + bias[ft]);
    }
  }
}

// ---------------- conv1d (MFMA, 64 rows/wave) + bias + residual(f32) + LN + relu ----------------
// LAST=false: write h (f32) + hb (bf16).  LAST=true: fused output projection, write out.
template<bool LAST>
__global__ __launch_bounds__(256) void k_conv(const unsigned short* __restrict__ Cin,
                                              const unsigned short* __restrict__ Wvt,
                                              const float* __restrict__ cb, const float* __restrict__ lg,
                                              const float* __restrict__ lb,
                                              float* __restrict__ H, unsigned short* __restrict__ Hb,
                                              const float* __restrict__ ow, const float* __restrict__ ob,
                                              float* __restrict__ out, int b0){
  int t = threadIdx.x;
  int lane = t & 63, w = t >> 6;
  int c = lane & 15, g = lane >> 4;
  int rbase = blockIdx.x*256 + w*64;
  f32x4 acc[4][8];
  #pragma unroll
  for(int i=0;i<4;i++)
    #pragma unroll
    for(int j=0;j<8;j++) acc[i][j] = (f32x4){0.f,0.f,0.f,0.f};
  short8 zf = {0,0,0,0,0,0,0,0};
  for(int ic=0; ic<4; ic++){
    int koff = ic*32 + 8*g;
    #pragma unroll
    for(int kw=0; kw<3; kw++){
      short8 af[4];
      #pragma unroll
      for(int rt=0; rt<4; rt++){
        int rowA = rbase + rt*16 + c + (kw-1)*BCK;   // node neighbor = m +/- BCK
        af[rt] = ((unsigned)rowA < (unsigned)NMC) ? *(const short8*)(Cin + (size_t)rowA*NH + koff) : zf;
      }
      #pragma unroll
      for(int ft=0; ft<8; ft++){
        short8 bf_ = *(const short8*)(Wvt + (((size_t)kw*NH + 16*ft + c)<<7) + koff);
        #pragma unroll
        for(int rt=0; rt<4; rt++)
          acc[rt][ft] = __builtin_amdgcn_mfma_f32_16x16x32_bf16(af[rt], bf_, acc[rt][ft], 0, 0, 0);
      }
    }
  }
  float cbv[8], gv[8], bv[8];
  #pragma unroll
  for(int ft=0; ft<8; ft++){
    int f = 16*ft + c;
    cbv[ft] = cb[f]; gv[ft] = lg[f]; bv[ft] = lb[f];
  }
  #pragma unroll
  for(int rt=0; rt<4; rt++){
    #pragma unroll
    for(int r=0;r<4;r++){
      int row = rbase + rt*16 + 4*g + r;
      size_t rbs = (size_t)row*NH;
      float vals[8];
      float s = 0.f;
      #pragma unroll
      for(int ft=0; ft<8; ft++){
        float res = H[rbs + 16*ft + c];
        float v = acc[rt][ft][r] + cbv[ft] + res;
        vals[ft] = v;
        s += v;
      }
      s += __shfl_xor(s,1,64); s += __shfl_xor(s,2,64);
      s += __shfl_xor(s,4,64); s += __shfl_xor(s,8,64);
      float mu = s * (1.f/128.f);
      float q = 0.f;
      #pragma unroll
      for(int ft=0; ft<8; ft++){ float d = vals[ft]-mu; q += d*d; }
      q += __shfl_xor(q,1,64); q += __shfl_xor(q,2,64);
      q += __shfl_xor(q,4,64); q += __shfl_xor(q,8,64);
      float rs = rsqrtf(q*(1.f/128.f) + EPSV);
      if(!LAST){
        #pragma unroll
        for(int ft=0; ft<8; ft++){
          float y = (vals[ft]-mu)*rs*gv[ft] + bv[ft];
          y = fmaxf(y, 0.f);
          H[rbs + 16*ft + c] = y;
          Hb[rbs + 16*ft + c] = f2bf(y);
        }
      } else {
        float p0=0.f, p1=0.f, p2=0.f;
        #pragma unroll
        for(int ft=0; ft<8; ft++){
          float y = (vals[ft]-mu)*rs*gv[ft] + bv[ft];
          y = fmaxf(y, 0.f);
          int f = 16*ft + c;
          p0 = fmaf(y, ow[f*3+0], p0);
          p1 = fmaf(y, ow[f*3+1], p1);
          p2 = fmaf(y, ow[f*3+2], p2);
        }
        p0 += __shfl_xor(p0,1,64); p0 += __shfl_xor(p0,2,64);
        p0 += __shfl_xor(p0,4,64); p0 += __shfl_xor(p0,8,64);
        p1 += __shfl_xor(p1,1,64); p1 += __shfl_xor(p1,2,64);
        p1 += __shfl_xor(p1,4,64); p1 += __shfl_xor(p1,8,64);
        p2 += __shfl_xor(p2,1,64); p2 += __shfl_xor(p2,2,64);
        p2 += __shfl_xor(p2,4,64); p2 += __shfl_xor(p2,8,64);
        if(c==0){
          int n = row >> 3, bl = b0 + (row & 7);
          out[((size_t)bl*NP+0)*NN+n] = p0 + ob[0];
          out[((size_t)bl*NP+1)*NN+n] = p1 + ob[1];
          out[((size_t)bl*NP+2)*NN+n] = p2 + ob[2];
        }
      }
    }
  }
}

extern "C" void kernel_launch(void* const* d_in, const int* in_sizes, int n_in,
                              void* d_out, int out_size, void* d_ws, size_t ws_size,
                              hipStream_t stream) {
  const float* x      = (const float*)d_in[0];
  const int*   ei     = (const int*)d_in[1];
  const float* in_w   = (const float*)d_in[2];
  const float* in_b   = (const float*)d_in[3];
  const float* cheb_w = (const float*)d_in[4];
  const float* cheb_b = (const float*)d_in[5];
  const float* conv_w = (const float*)d_in[6];
  const float* conv_b = (const float*)d_in[7];
  const float* ln_g   = (const float*)d_in[8];
  const float* ln_b   = (const float*)d_in[9];
  const float* out_w  = (const float*)d_in[10];
  const float* out_b  = (const float*)d_in[11];
  float* out = (float*)d_out;

  char* ws = (char*)d_ws;
  size_t off = 0;
  auto alloc = [&](size_t bytes)->void*{
    void* p = ws + off;
    off += (bytes + 255) & ~(size_t)255;
    return p;
  };
  // ---- fixed region (~6.3 MB) ----
  int* flag    = (int*)alloc(4);
  int* deg     = (int*)alloc(NN*4);
  int* cnt     = (int*)alloc(NN*4);
  int* fill    = (int*)alloc(NN*4);
  int* offs    = (int*)alloc((NN+1)*4);
  float* dis   = (float*)alloc(NN*4);
  int2* edata  = (int2*)alloc((size_t)NE*8);
  unsigned short* Wct = (unsigned short*)alloc((size_t)NL*3*NH*NH*2);
  unsigned short* Wvt = (unsigned short*)alloc((size_t)NL*3*NH*NH*2);
  // ---- chunk activation buffers: 82 + 3*41 MB = 205 MB ----
  const size_t fullb = ((size_t)NMC*NH*4 + 255) & ~(size_t)255;
  const size_t halfb = ((size_t)NMC*NH*2 + 255) & ~(size_t)255;
  float*          h   = (float*)alloc(fullb);
  unsigned short* hb  = (unsigned short*)alloc(halfb);
  unsigned short* t1b = (unsigned short*)alloc(halfb);
  unsigned short* t2b = (unsigned short*)alloc(halfb);

  hipMemsetAsync(deg, 0, NN*4, stream);
  hipMemsetAsync(cnt, 0, NN*4, stream);
  hipMemsetAsync(fill, 0, NN*4, stream);

  k_detect<<<1,256,0,stream>>>(ei,flag);
  k_count<<<(NE+255)/256,256,0,stream>>>(ei,flag,deg,cnt);
  k_dis<<<(NN+255)/256,256,0,stream>>>(deg,dis);
  k_scan<<<1,1024,0,stream>>>(cnt,offs);
  k_scatter<<<(NE+255)/256,256,0,stream>>>(ei,flag,offs,fill,dis,edata);
  k_prepw<<<(NL*3*NH*NH+255)/256,256,0,stream>>>(cheb_w,conv_w,Wct,Wvt);

  for(int b0=0; b0<NB; b0+=BCK){
    k_inproj<<<NMC/4,256,0,stream>>>(x,in_w,in_b,h,(unsigned int*)hb,b0);
    for(int l=0;l<NL;l++){
      k_prop<false><<<NN,PROP_T,0,stream>>>((const uint4*)hb,  nullptr,
                                            (uint4*)t1b, offs, edata);
      k_prop<true ><<<NN,PROP_T,0,stream>>>((const uint4*)t1b, (const uint4*)hb,
                                            (uint4*)t2b, offs, edata);
      k_cheb<<<NGEMM,256,0,stream>>>(hb, t1b, t2b, Wct + (size_t)l*3*NH*NH,
                                     cheb_b + l*NH, t2b);
      if(l==0)
        k_conv<false><<<NGEMM,256,0,stream>>>(t2b, Wvt + (size_t)l*3*NH*NH, conv_b + l*NH,
                                              ln_g + l*NH, ln_b + l*NH, h, hb,
                                              out_w, out_b, out, b0);
      else
        k_conv<true ><<<NGEMM,256,0,stream>>>(t2b, Wvt + (size_t)l*3*NH*NH, conv_b + l*NH,
                                              ln_g + l*NH, ln_b + l*NH, h, hb,
                                              out_w, out_b, out, b0);
    }
  }
}